// Round 4
// baseline (1175.200 us; speedup 1.0000x reference)
//
#include <hip/hip_runtime.h>
#include <hip/hip_bf16.h>

#define NG 4
#define ID 128
#define HD 128
#define TH 384      // 3*HD
#define NB 32
#define NT 1000
#define XW (NG*ID)  // 512
#define OW (NG*HD)  // 512
#define GSTRIDE (NG*TH)  // 1536 f16 elems per (b,t)

typedef _Float16 v8h __attribute__((ext_vector_type(8)));
typedef __attribute__((ext_vector_type(4))) float v4f;

union U4 { ushort4 u; _Float16 h[4]; };
union PK { _Float16 h[4]; uint2 u; };

__device__ __forceinline__ float sigm(float v) {
    return __fdividef(1.f, 1.f + __expf(-v));
}
__device__ __forceinline__ float tanh_(float v) {
    v = fminf(fmaxf(v, -15.f), 15.f);
    float e2 = __expf(2.f * v);
    return __fdividef(e2 - 1.f, e2 + 1.f);
}

// ---------------- Phase 1: register-only fp16 MFMA GEMM.
// gi[(b*T+t)*NG+g][n] = x[b,t,g*128:+128] @ w_ih[g]^T + b_ih[g], stored f16.
// grid (3, 250, 4), block 256 (4 waves; wave w: m-half w&1, n-half w>>1).
__global__ __launch_bounds__(256) void gi_gemm_f16(
    const float* __restrict__ x,
    const float* __restrict__ w_ih,
    const float* __restrict__ b_ih,
    _Float16* __restrict__ gi)
{
    const int tid  = threadIdx.x;
    const int w    = tid >> 6, l = tid & 63;
    const int lr   = l & 15, lq = l >> 4;
    const int g    = blockIdx.z;
    const int n0   = blockIdx.x * 128 + (w >> 1) * 64;   // gate-col base
    const int row0 = blockIdx.y * 128 + (w & 1) * 64;    // (b*T+t) row base

    v4f acc[4][4];
    #pragma unroll
    for (int mi = 0; mi < 4; ++mi)
        #pragma unroll
        for (int ni = 0; ni < 4; ++ni)
            acc[mi][ni] = (v4f){0.f, 0.f, 0.f, 0.f};

    #pragma unroll
    for (int kf = 0; kf < 4; ++kf) {
        v8h bf[4], af[4];
        #pragma unroll
        for (int ni = 0; ni < 4; ++ni) {
            const float* p = &w_ih[(size_t)(g * TH + n0 + ni * 16 + lr) * ID + kf * 32 + lq * 8];
            float4 f0 = *reinterpret_cast<const float4*>(p);
            float4 f1 = *reinterpret_cast<const float4*>(p + 4);
            v8h v;
            v[0]=(_Float16)f0.x; v[1]=(_Float16)f0.y; v[2]=(_Float16)f0.z; v[3]=(_Float16)f0.w;
            v[4]=(_Float16)f1.x; v[5]=(_Float16)f1.y; v[6]=(_Float16)f1.z; v[7]=(_Float16)f1.w;
            bf[ni] = v;
        }
        #pragma unroll
        for (int mi = 0; mi < 4; ++mi) {
            const float* p = &x[(size_t)(row0 + mi * 16 + lr) * XW + g * ID + kf * 32 + lq * 8];
            float4 f0 = *reinterpret_cast<const float4*>(p);
            float4 f1 = *reinterpret_cast<const float4*>(p + 4);
            v8h v;
            v[0]=(_Float16)f0.x; v[1]=(_Float16)f0.y; v[2]=(_Float16)f0.z; v[3]=(_Float16)f0.w;
            v[4]=(_Float16)f1.x; v[5]=(_Float16)f1.y; v[6]=(_Float16)f1.z; v[7]=(_Float16)f1.w;
            af[mi] = v;
        }
        #pragma unroll
        for (int mi = 0; mi < 4; ++mi)
            #pragma unroll
            for (int ni = 0; ni < 4; ++ni)
                acc[mi][ni] = __builtin_amdgcn_mfma_f32_16x16x32_f16(
                    af[mi], bf[ni], acc[mi][ni], 0, 0, 0);
    }

    float bias[4];
    #pragma unroll
    for (int ni = 0; ni < 4; ++ni)
        bias[ni] = b_ih[g * TH + n0 + ni * 16 + lr];

    #pragma unroll
    for (int mi = 0; mi < 4; ++mi)
        #pragma unroll
        for (int ni = 0; ni < 4; ++ni) {
            const int n = n0 + ni * 16 + lr;
            #pragma unroll
            for (int r = 0; r < 4; ++r) {
                const int m = row0 + mi * 16 + lq * 4 + r;
                gi[((size_t)m * NG + g) * TH + n] = (_Float16)(acc[mi][ni][r] + bias[ni]);
            }
        }
}

// ---------------- Phase 2: MFMA recurrence, 1 barrier/step.
// grid 32 (g, 4-batch chunk), block 512 (8 waves). Wave w: gate rows 16w..16w+15.
// Lane (lr,lq): acc reg r holds gh[j=16w+4lq+r][batch=lr] -> gates computed
// in-register on lanes lr<4. h double-buffered; gi ring-4 + depth-2 prefetch.
__global__ __launch_bounds__(512) void gru_rec2(
    const _Float16* __restrict__ gi,
    const float* __restrict__ w_hh,
    const float* __restrict__ b_hh,
    float* __restrict__ out)
{
    __shared__ ushort h_lds[2][16][152];    // [buf][batch][k pad 152] (304B rows)
    __shared__ ushort gi_lds[4][4][392];    // [ring][batch][384 pad 392]

    const int tid = threadIdx.x;
    const int w   = tid >> 6, l = tid & 63;
    const int lr  = l & 15, lq = l >> 4;
    const int g   = blockIdx.x & 3;
    const int b0  = (blockIdx.x >> 2) * 4;

    // ---- w_hh A-frags (f16), once. a[i]: m-tile w+8i (gate i), rows 16w..16w+15.
    v8h a[3][4];
    #pragma unroll
    for (int i = 0; i < 3; ++i) {
        const int mrow = (w + 8 * i) * 16 + lr;
        #pragma unroll
        for (int kf = 0; kf < 4; ++kf) {
            const float* p = &w_hh[(size_t)(g * TH + mrow) * HD + kf * 32 + lq * 8];
            float4 f0 = *reinterpret_cast<const float4*>(p);
            float4 f1 = *reinterpret_cast<const float4*>(p + 4);
            v8h v;
            v[0]=(_Float16)f0.x; v[1]=(_Float16)f0.y; v[2]=(_Float16)f0.z; v[3]=(_Float16)f0.w;
            v[4]=(_Float16)f1.x; v[5]=(_Float16)f1.y; v[6]=(_Float16)f1.z; v[7]=(_Float16)f1.w;
            a[i][kf] = v;
        }
    }

    // ---- gate identity (valid for lr<4): batch nb=lr, j base jb=16w+4lq
    const int nb = lr & 3;
    const int jb = w * 16 + lq * 4;
    const v4f bRv = *reinterpret_cast<const v4f*>(&b_hh[g * TH + jb]);
    const v4f bZv = *reinterpret_cast<const v4f*>(&b_hh[g * TH + 128 + jb]);
    const v4f bNv = *reinterpret_cast<const v4f*>(&b_hh[g * TH + 256 + jb]);
    float hprev[4] = {0.f, 0.f, 0.f, 0.f};
    float* outp = out + (size_t)(b0 + nb) * NT * OW + g * HD + jb;

    // ---- zero both h buffers (cols >=4 stay zero forever)
    for (int i = tid; i < 2 * 16 * 152 / 2; i += 512)
        reinterpret_cast<unsigned int*>(h_lds)[i] = 0u;

    // ---- gi staging: 192 threads move 16B each; ring-4, 2 steps in flight
    const int bb  = tid / 48;
    const int seg = tid - bb * 48;
    const bool stg = (tid < 192);
    const _Float16* gbase = gi + ((size_t)(b0 + bb) * NT * NG + g) * TH + seg * 8;

    uint4 pre0 = {0,0,0,0}, pre1 = {0,0,0,0}, pre2 = {0,0,0,0}, pre3 = {0,0,0,0};
    if (stg) {
        uint4 v0 = *reinterpret_cast<const uint4*>(gbase);
        uint4 v1 = *reinterpret_cast<const uint4*>(gbase + GSTRIDE);
        pre2 = *reinterpret_cast<const uint4*>(gbase + 2 * (size_t)GSTRIDE);
        pre3 = *reinterpret_cast<const uint4*>(gbase + 3 * (size_t)GSTRIDE);
        *reinterpret_cast<uint4*>(&gi_lds[0][bb][seg * 8]) = v0;
        *reinterpret_cast<uint4*>(&gi_lds[1][bb][seg * 8]) = v1;
    }
    __syncthreads();

#define MF(i, k, B) __builtin_amdgcn_mfma_f32_16x16x32_f16(a[i][k], B, ac##i, 0, 0, 0)

#define STEP(P, PRE_WR, PRE_ISS)                                                   \
    {                                                                              \
        const int t = tb + (P);                                                    \
        if (stg) {                                                                 \
            int tl = t + 4; if (tl > NT - 1) tl = NT - 1;                          \
            PRE_ISS = *reinterpret_cast<const uint4*>(gbase + (size_t)tl * GSTRIDE); \
            *reinterpret_cast<uint4*>(&gi_lds[((P) + 2) & 3][bb][seg * 8]) = PRE_WR; \
        }                                                                          \
        const char* hb = reinterpret_cast<const char*>(&h_lds[(P) & 1][0][0])      \
                         + lr * 304 + lq * 16;                                     \
        v8h bfr0 = *reinterpret_cast<const v8h*>(hb);                              \
        v8h bfr1 = *reinterpret_cast<const v8h*>(hb + 64);                         \
        v8h bfr2 = *reinterpret_cast<const v8h*>(hb + 128);                        \
        v8h bfr3 = *reinterpret_cast<const v8h*>(hb + 192);                        \
        v4f ac0 = {0.f,0.f,0.f,0.f}, ac1 = ac0, ac2 = ac0;                         \
        ac0 = MF(0, 0, bfr0); ac1 = MF(1, 0, bfr0); ac2 = MF(2, 0, bfr0);          \
        ac0 = MF(0, 1, bfr1); ac1 = MF(1, 1, bfr1); ac2 = MF(2, 1, bfr1);          \
        ac0 = MF(0, 2, bfr2); ac1 = MF(1, 2, bfr2); ac2 = MF(2, 2, bfr2);          \
        ac0 = MF(0, 3, bfr3); ac1 = MF(1, 3, bfr3); ac2 = MF(2, 3, bfr3);          \
        if (lr < 4) {                                                              \
            U4 uR, uZ, uN;                                                         \
            uR.u = *reinterpret_cast<const ushort4*>(&gi_lds[(P) & 3][nb][jb]);    \
            uZ.u = *reinterpret_cast<const ushort4*>(&gi_lds[(P) & 3][nb][128 + jb]); \
            uN.u = *reinterpret_cast<const ushort4*>(&gi_lds[(P) & 3][nb][256 + jb]); \
            float hnv[4];                                                          \
            _Pragma("unroll")                                                      \
            for (int r = 0; r < 4; ++r) {                                          \
                float rr = sigm((float)uR.h[r] + ac0[r] + bRv[r]);                 \
                float zz = sigm((float)uZ.h[r] + ac1[r] + bZv[r]);                 \
                float nn = tanh_((float)uN.h[r] + rr * (ac2[r] + bNv[r]));         \
                hnv[r] = fmaf(zz, hprev[r] - nn, nn);                              \
                hprev[r] = hnv[r];                                                 \
            }                                                                      \
            PK pk;                                                                 \
            pk.h[0] = (_Float16)hnv[0]; pk.h[1] = (_Float16)hnv[1];                \
            pk.h[2] = (_Float16)hnv[2]; pk.h[3] = (_Float16)hnv[3];                \
            *reinterpret_cast<uint2*>(&h_lds[((P) + 1) & 1][nb][jb]) = pk.u;       \
            *reinterpret_cast<float4*>(outp + (size_t)t * OW) =                    \
                make_float4(hnv[0], hnv[1], hnv[2], hnv[3]);                       \
        }                                                                          \
        __syncthreads();                                                           \
    }

    for (int tb = 0; tb < NT; tb += 4) {
        STEP(0, pre2, pre0)   // write data tb+2 -> buf2, issue tb+4 -> pre0
        STEP(1, pre3, pre1)   // write data tb+3 -> buf3, issue tb+5 -> pre1
        STEP(2, pre0, pre2)   // write data tb+4 -> buf0, issue tb+6 -> pre2
        STEP(3, pre1, pre3)   // write data tb+5 -> buf1, issue tb+7 -> pre3
    }
#undef STEP
#undef MF
}

extern "C" void kernel_launch(void* const* d_in, const int* in_sizes, int n_in,
                              void* d_out, int out_size, void* d_ws, size_t ws_size,
                              hipStream_t stream) {
    const float* x    = (const float*)d_in[0];
    const float* w_ih = (const float*)d_in[1];
    const float* w_hh = (const float*)d_in[2];
    const float* b_ih = (const float*)d_in[3];
    const float* b_hh = (const float*)d_in[4];
    float* out = (float*)d_out;
    _Float16* gi = (_Float16*)d_ws;   // [B*T, G, 384] f16 = 98.3 MB

    dim3 g1(3, 250, NG);
    gi_gemm_f16<<<g1, 256, 0, stream>>>(x, w_ih, b_ih, gi);
    gru_rec2<<<NB * NG / 4, 512, 0, stream>>>(gi, w_hh, b_hh, out);
}

// Round 7
// 775.416 us; speedup vs baseline: 1.5156x; 1.5156x over previous
//
#include <hip/hip_runtime.h>
#include <hip/hip_bf16.h>

#define NG 4
#define ID 128
#define HD 128
#define TH 384      // 3*HD
#define NB 32
#define NT 1000
#define XW (NG*ID)  // 512
#define OW (NG*HD)  // 512
#define GSTRIDE (NG*TH)  // 1536 f16 per (b,t)

typedef _Float16 v8h __attribute__((ext_vector_type(8)));
typedef __attribute__((ext_vector_type(4))) float v4f;

__device__ __forceinline__ float sigm(float v) {
    return __fdividef(1.f, 1.f + __expf(-v));
}
__device__ __forceinline__ float tanh_(float v) {
    v = fminf(fmaxf(v, -15.f), 15.f);
    float e2 = __expf(2.f * v);
    return __fdividef(e2 - 1.f, e2 + 1.f);
}
__device__ __forceinline__ ushort f2h(float x) {
    _Float16 h = (_Float16)x;
    return __builtin_bit_cast(unsigned short, h);
}
__device__ __forceinline__ void gl2lds16(const void* g, void* l) {
    __builtin_amdgcn_global_load_lds(
        (const __attribute__((address_space(1))) unsigned int*)g,
        (__attribute__((address_space(3))) unsigned int*)l, 16, 0, 0);
}

// ---------------- Phase 1 (R4, proven): gi = x @ w_ih^T + b_ih, f16 MFMA.
// grid (3, 250, 4), block 256.
__global__ __launch_bounds__(256) void gi_gemm_f16(
    const float* __restrict__ x,
    const float* __restrict__ w_ih,
    const float* __restrict__ b_ih,
    _Float16* __restrict__ gi)
{
    const int tid  = threadIdx.x;
    const int w    = tid >> 6, l = tid & 63;
    const int lr   = l & 15, lq = l >> 4;
    const int g    = blockIdx.z;
    const int n0   = blockIdx.x * 128 + (w >> 1) * 64;   // gate-col base
    const int row0 = blockIdx.y * 128 + (w & 1) * 64;    // (b*T+t) row base

    v4f acc[4][4];
    #pragma unroll
    for (int mi = 0; mi < 4; ++mi)
        #pragma unroll
        for (int ni = 0; ni < 4; ++ni)
            acc[mi][ni] = (v4f){0.f, 0.f, 0.f, 0.f};

    #pragma unroll
    for (int kf = 0; kf < 4; ++kf) {
        v8h bf[4], af[4];
        #pragma unroll
        for (int ni = 0; ni < 4; ++ni) {
            const float* p = &w_ih[(size_t)(g * TH + n0 + ni * 16 + lr) * ID + kf * 32 + lq * 8];
            float4 f0 = *reinterpret_cast<const float4*>(p);
            float4 f1 = *reinterpret_cast<const float4*>(p + 4);
            v8h v;
            v[0]=(_Float16)f0.x; v[1]=(_Float16)f0.y; v[2]=(_Float16)f0.z; v[3]=(_Float16)f0.w;
            v[4]=(_Float16)f1.x; v[5]=(_Float16)f1.y; v[6]=(_Float16)f1.z; v[7]=(_Float16)f1.w;
            bf[ni] = v;
        }
        #pragma unroll
        for (int mi = 0; mi < 4; ++mi) {
            const float* p = &x[(size_t)(row0 + mi * 16 + lr) * XW + g * ID + kf * 32 + lq * 8];
            float4 f0 = *reinterpret_cast<const float4*>(p);
            float4 f1 = *reinterpret_cast<const float4*>(p + 4);
            v8h v;
            v[0]=(_Float16)f0.x; v[1]=(_Float16)f0.y; v[2]=(_Float16)f0.z; v[3]=(_Float16)f0.w;
            v[4]=(_Float16)f1.x; v[5]=(_Float16)f1.y; v[6]=(_Float16)f1.z; v[7]=(_Float16)f1.w;
            af[mi] = v;
        }
        #pragma unroll
        for (int mi = 0; mi < 4; ++mi)
            #pragma unroll
            for (int ni = 0; ni < 4; ++ni)
                acc[mi][ni] = __builtin_amdgcn_mfma_f32_16x16x32_f16(
                    af[mi], bf[ni], acc[mi][ni], 0, 0, 0);
    }

    float bias[4];
    #pragma unroll
    for (int ni = 0; ni < 4; ++ni)
        bias[ni] = b_ih[g * TH + n0 + ni * 16 + lr];

    #pragma unroll
    for (int mi = 0; mi < 4; ++mi)
        #pragma unroll
        for (int ni = 0; ni < 4; ++ni) {
            const int n = n0 + ni * 16 + lr;
            #pragma unroll
            for (int r = 0; r < 4; ++r) {
                const int m = row0 + mi * 16 + lq * 4 + r;
                gi[((size_t)m * NG + g) * TH + n] = (_Float16)(acc[mi][ni][r] + bias[ni]);
            }
        }
}

// ---------------- Phase 2: MFMA recurrence, 1 __syncthreads/step.
// gi staged 8 steps/tile via global_load_lds. gh redistribution via
// per-wave LDS scratch (R3-proven routing; intra-wave => no extra barrier).
// grid 32 (g, 4-batch chunk), block 512 (8 waves).
__global__ __launch_bounds__(512) void gru_rec5(
    const _Float16* __restrict__ gi,
    const float* __restrict__ w_hh,
    const float* __restrict__ b_hh,
    float* __restrict__ out)
{
    __shared__ __align__(16) ushort h_lds[2][16][152];     // ping-pong h, 304B rows
    __shared__ __align__(16) _Float16 tile[2][4 * 3080];   // 8t x 384 f16 per batch + 16B pad
    __shared__ __align__(16) float gh_s[8][3][4][20];      // per-wave scratch, 80B rows

    const int tid = threadIdx.x;
    const int w = tid >> 6, l = tid & 63;
    const int lr = l & 15, lq = l >> 4;
    const int g  = blockIdx.x & 3;
    const int b0 = (blockIdx.x >> 2) * 4;

    // ---- w_hh A-frags (f16), once. a[i]: gate i, rows 16w..16w+15.
    v8h a[3][4];
    #pragma unroll
    for (int i = 0; i < 3; ++i) {
        const int mrow = (w + 8 * i) * 16 + lr;
        #pragma unroll
        for (int kf = 0; kf < 4; ++kf) {
            const float* p = &w_hh[(size_t)(g * TH + mrow) * HD + kf * 32 + lq * 8];
            float4 f0 = *reinterpret_cast<const float4*>(p);
            float4 f1 = *reinterpret_cast<const float4*>(p + 4);
            v8h v;
            v[0]=(_Float16)f0.x; v[1]=(_Float16)f0.y; v[2]=(_Float16)f0.z; v[3]=(_Float16)f0.w;
            v[4]=(_Float16)f1.x; v[5]=(_Float16)f1.y; v[6]=(_Float16)f1.z; v[7]=(_Float16)f1.w;
            a[i][kf] = v;
        }
    }

    // ---- gate identity: 1 element/lane: (j = 16w + jt, jt = l>>2, batch nb = l&3)
    const int jt = l >> 2, nb = l & 3;
    const int j  = w * 16 + jt;
    const float bR = b_hh[g * TH + j];
    const float bZ = b_hh[g * TH + 128 + j];
    const float bN = b_hh[g * TH + 256 + j];
    float hprev = 0.f;
    float* outp = out + (size_t)(b0 + nb) * NT * OW + g * HD + j;

    // ---- zero both h buffers
    for (int i = tid; i < 2 * 16 * 152 / 2; i += 512)
        reinterpret_cast<unsigned int*>(h_lds)[i] = 0u;

    // ---- DMA descriptors: 24 instrs/tile, 3 per wave. q = w*3+i ->
    // batch q/6, 1KB-chunk c = q%6 of the batch's 6144B (8t x 768B) region.
    const _Float16* gsrc[3];
    _Float16* ldst[2][3];
    #pragma unroll
    for (int i = 0; i < 3; ++i) {
        const int qq = w * 3 + i;
        const int batch = qq / 6, c = qq % 6;
        const int e = c * 512 + l * 8;           // f16 offset in batch region
        const int t_rel = e / 384, idx = e - t_rel * 384;
        gsrc[i] = gi + ((size_t)(b0 + batch) * NT + t_rel) * GSTRIDE + g * TH + idx;
        ldst[0][i] = &tile[0][batch * 3080 + c * 512];
        ldst[1][i] = &tile[1][batch * 3080 + c * 512];
    }

    // ---- prologue: tile 0 -> buf 0
    #pragma unroll
    for (int i = 0; i < 3; ++i) gl2lds16(gsrc[i], ldst[0][i]);
    __syncthreads();

#define MF(i, k, B) __builtin_amdgcn_mfma_f32_16x16x32_f16(a[i][k], B, ac##i, 0, 0, 0)

    for (int T = 0; T < NT / 8; ++T) {
        const int cbuf = T & 1;
        // issue next tile's DMA burst (drains at end of step k=0)
        if (T < NT / 8 - 1) {
            const size_t go = (size_t)((T + 1) * 8) * GSTRIDE;
            #pragma unroll
            for (int i = 0; i < 3; ++i)
                gl2lds16(gsrc[i] + go, ldst[cbuf ^ 1][i]);
        }
        const _Float16* gl0 = &tile[cbuf][nb * 3080];
        float hv[8];
        #pragma unroll
        for (int k = 0; k < 8; ++k) {
            const char* hb = reinterpret_cast<const char*>(&h_lds[k & 1][0][0])
                             + lr * 304 + lq * 16;
            v8h bf0 = *reinterpret_cast<const v8h*>(hb);
            v8h bf1 = *reinterpret_cast<const v8h*>(hb + 64);
            v8h bf2 = *reinterpret_cast<const v8h*>(hb + 128);
            v8h bf3 = *reinterpret_cast<const v8h*>(hb + 192);
            v4f ac0 = {0.f,0.f,0.f,0.f}, ac1 = ac0, ac2 = ac0;
            ac0 = MF(0,0,bf0); ac1 = MF(1,0,bf0); ac2 = MF(2,0,bf0);
            ac0 = MF(0,1,bf1); ac1 = MF(1,1,bf1); ac2 = MF(2,1,bf1);
            ac0 = MF(0,2,bf2); ac1 = MF(1,2,bf2); ac2 = MF(2,2,bf2);
            ac0 = MF(0,3,bf3); ac1 = MF(1,3,bf3); ac2 = MF(2,3,bf3);

            // ---- gh redistribution: R3-proven scatter/gather, per-wave
            // scratch, same-wave DS ordering (no barrier needed).
            // scatter: reg r of lane (lr<4, lq) = gh[j_t = 4lq+r][batch = lr]
            if (lr < 4) {
                *reinterpret_cast<v4f*>(&gh_s[w][0][lr][lq * 4]) = ac0;
                *reinterpret_cast<v4f*>(&gh_s[w][1][lr][lq * 4]) = ac1;
                *reinterpret_cast<v4f*>(&gh_s[w][2][lr][lq * 4]) = ac2;
            }
            float ghr = gh_s[w][0][nb][jt];
            float ghz = gh_s[w][1][nb][jt];
            float ghn = gh_s[w][2][nb][jt];

            const _Float16* gl = gl0 + k * 384;
            float iR = (float)gl[j], iZ = (float)gl[128 + j], iN = (float)gl[256 + j];
            float rr = sigm(iR + ghr + bR);
            float zz = sigm(iZ + ghz + bZ);
            float nn = tanh_(iN + rr * (ghn + bN));
            float hn = fmaf(zz, hprev - nn, nn);
            hprev = hn;
            hv[k] = hn;
            float hp2 = __shfl_xor(hn, 4, 64);    // partner j^1, same nb
            if ((l & 4) == 0) {
                unsigned int wv = (unsigned int)f2h(hn) | ((unsigned int)f2h(hp2) << 16);
                *reinterpret_cast<unsigned int*>(&h_lds[(k + 1) & 1][nb][j]) = wv;
            }
            __syncthreads();
        }
        // dump 8 outputs (stores drain later; no in-loop dependence)
        const size_t ob = (size_t)(T * 8) * OW;
        #pragma unroll
        for (int k = 0; k < 8; ++k)
            outp[ob + (size_t)k * OW] = hv[k];
    }
#undef MF
}

extern "C" void kernel_launch(void* const* d_in, const int* in_sizes, int n_in,
                              void* d_out, int out_size, void* d_ws, size_t ws_size,
                              hipStream_t stream) {
    const float* x    = (const float*)d_in[0];
    const float* w_ih = (const float*)d_in[1];
    const float* w_hh = (const float*)d_in[2];
    const float* b_ih = (const float*)d_in[3];
    const float* b_hh = (const float*)d_in[4];
    float* out = (float*)d_out;
    _Float16* gi = (_Float16*)d_ws;   // [B*T, G, 384] f16 = 98.3 MB

    dim3 g1(3, 250, NG);
    gi_gemm_f16<<<g1, 256, 0, stream>>>(x, w_ih, b_ih, gi);
    gru_rec5<<<NB * NG / 4, 512, 0, stream>>>(gi, w_hh, b_hh, out);
}